// Round 2
// 1834.198 us; speedup vs baseline: 1.0697x; 1.0697x over previous
//
#include <hip/hip_runtime.h>
#include <math.h>

typedef __attribute__((ext_vector_type(8))) short short8;
typedef __attribute__((ext_vector_type(8))) __bf16 bf16x8;
typedef __attribute__((ext_vector_type(4))) float f32x4;

static constexpr int H = 1024, LNUM = 4, SEQ = 2048, BATCH = 2;
static constexpr int TOK = BATCH * SEQ;       // 4096
static constexpr int NI = 4096, QKVD = H + 128; // 1152

__device__ __forceinline__ short f2bf(float f) {   // RNE fp32->bf16 bits
  union { float f; unsigned u; } c; c.f = f;
  return (short)((c.u + 0x7fffu + ((c.u >> 16) & 1u)) >> 16);
}

__device__ __forceinline__ void gl_lds16(const short* g, short* l) {
  __builtin_amdgcn_global_load_lds(
      (const __attribute__((address_space(1))) unsigned*)g,
      (__attribute__((address_space(3))) unsigned*)l, 16, 0, 0);
}

__device__ __forceinline__ unsigned cvtpk_bf16(float lo, float hi) {
  unsigned r;
  asm("v_cvt_pk_bf16_f32 %0, %1, %2" : "=v"(r) : "v"(lo), "v"(hi));
  return r;
}

#define MFMA16(a, b, c) __builtin_amdgcn_mfma_f32_16x16x32_bf16(a, b, c, 0, 0, 0)

// ---------------------------------------------------------------- embedding
__global__ __launch_bounds__(256) void embed_kernel(
    const int* __restrict__ ids, const int* __restrict__ pos,
    const float* __restrict__ wte, const float* __restrict__ wpe,
    float* __restrict__ h) {
  int i = blockIdx.x * 256 + threadIdx.x;
  int tok = i >> 10, d = i & 1023;
  h[i] = wte[(size_t)ids[tok] * H + d] + wpe[(size_t)pos[tok] * H + d];
}

// ---------------------------------------------------------------- fp32 -> bf16 cast (weights)
__global__ __launch_bounds__(256) void cast_kernel(
    const float* __restrict__ src, short* __restrict__ dst) {
  int i = blockIdx.x * 256 + threadIdx.x;
  float4 v = ((const float4*)src)[i];
  union { short s[4]; uint2 u; } p;
  p.s[0] = f2bf(v.x); p.s[1] = f2bf(v.y); p.s[2] = f2bf(v.z); p.s[3] = f2bf(v.w);
  ((uint2*)dst)[i] = p.u;
}

// ---------------------------------------------------------------- layernorm (fp32 in; bf16 or fp32 out)
template <bool BF16_OUT>
__global__ __launch_bounds__(256) void ln_kernel(
    const float* __restrict__ X, const float* __restrict__ w,
    const float* __restrict__ b, void* __restrict__ out) {
  int row = blockIdx.x;
  const float* x = X + (size_t)row * H;
  int tid = threadIdx.x, lane = tid & 63, wid = tid >> 6;
  float v[4];
#pragma unroll
  for (int i = 0; i < 4; i++) v[i] = x[tid + i * 256];
  float s = v[0] + v[1] + v[2] + v[3];
#pragma unroll
  for (int off = 32; off > 0; off >>= 1) s += __shfl_xor(s, off);
  __shared__ float red[8];
  if (lane == 0) red[wid] = s;
  __syncthreads();
  float mu = (red[0] + red[1] + red[2] + red[3]) * (1.0f / H);
  float q = 0.f;
#pragma unroll
  for (int i = 0; i < 4; i++) { float d = v[i] - mu; q += d * d; }
#pragma unroll
  for (int off = 32; off > 0; off >>= 1) q += __shfl_xor(q, off);
  if (lane == 0) red[4 + wid] = q;
  __syncthreads();
  float var = (red[4] + red[5] + red[6] + red[7]) * (1.0f / H);
  float inv = rsqrtf(var + 1e-5f);
#pragma unroll
  for (int i = 0; i < 4; i++) {
    int col = tid + i * 256;
    float r = (v[i] - mu) * inv * w[col] + b[col];
    if (BF16_OUT) ((short*)out)[(size_t)row * H + col] = f2bf(r);
    else          ((float*)out)[(size_t)row * H + col] = r;
  }
}

// ---------------------------------------------------------------- MFMA GEMM: C = A(M,K)bf16 * W(N,K)bf16^T + bias(f32)
// MODE 0: C(bf16) = r   MODE 1: C(f32) += r   MODE 2: C(bf16) = gelu(r)
// 128x128 tile, BK=32, 256 thr = 4 waves in 2x2 of 64x64; wave: 4x4 tiles of 16x16.
template <int MODE>
__global__ __launch_bounds__(256) void gemm_mfma(
    const short* __restrict__ A, const short* __restrict__ W,
    const float* __restrict__ bias, void* __restrict__ Cv,
    int M, int N, int K) {
  __shared__ short As[128 * 32];
  __shared__ short Bs[128 * 32];
  int tid = threadIdx.x, wave = tid >> 6, lane = tid & 63;
  int li = lane & 15, lg = lane >> 4;
  int row0 = blockIdx.y * 128, col0 = blockIdx.x * 128;
  int wm = (wave & 1) * 64, wn = (wave >> 1) * 64;
  f32x4 acc[4][4] = {};
  const short* Ab = A + (size_t)(row0 + (tid >> 2)) * K + (tid & 3) * 8;
  const short* Wb = W + (size_t)(col0 + (tid >> 2)) * K + (tid & 3) * 8;
  for (int k0 = 0; k0 < K; k0 += 32) {
    __syncthreads();                       // LDS free (prev compute done)
    gl_lds16(Ab + k0,            As + tid * 8);
    gl_lds16(Ab + k0 + 64 * K,   As + 2048 + tid * 8);
    gl_lds16(Wb + k0,            Bs + tid * 8);
    gl_lds16(Wb + k0 + 64 * K,   Bs + 2048 + tid * 8);
    __syncthreads();                       // drains vmcnt before barrier
    bf16x8 af[4], bfr[4];
#pragma unroll
    for (int i = 0; i < 4; ++i) {
      af[i]  = *(const bf16x8*)&As[(wm + i * 16 + li) * 32 + lg * 8];
      bfr[i] = *(const bf16x8*)&Bs[(wn + i * 16 + li) * 32 + lg * 8];
    }
#pragma unroll
    for (int i = 0; i < 4; ++i)
#pragma unroll
      for (int j = 0; j < 4; ++j) acc[i][j] = MFMA16(af[i], bfr[j], acc[i][j]);
  }
  // epilogue; C/D layout: col = li, row = lg*4 + reg
  float* Cf = (float*)Cv;
  short* Cs = (short*)Cv;
#pragma unroll
  for (int i = 0; i < 4; ++i) {
    int gr = row0 + wm + i * 16 + lg * 4;
#pragma unroll
    for (int j = 0; j < 4; ++j) {
      int gc = col0 + wn + j * 16 + li;
      float bv = bias[gc];
#pragma unroll
      for (int r = 0; r < 4; ++r) {
        float v = acc[i][j][r] + bv;
        size_t idx = (size_t)(gr + r) * N + gc;
        if (MODE == 1) {
          Cf[idx] += v;
        } else if (MODE == 2) {
          v = 0.5f * v * (1.0f + erff(v * 0.70710678118654752f));
          Cs[idx] = f2bf(v);
        } else {
          Cs[idx] = f2bf(v);
        }
      }
    }
  }
}

// ---------------------------------------------------------------- V transpose: qkv V cols -> VT[b][d][t]
// One pass per layer; VT tile then shared by all 16 heads (was re-transposed per head before).
__global__ __launch_bounds__(256) void vtrans_kernel(
    const short* __restrict__ qkv, short* __restrict__ vt) {
  int i = blockIdx.x * 256 + threadIdx.x;   // 2*64*256 threads
  int d  = i & 63;
  int tc = (i >> 6) & 255;                  // t-chunk of 8
  int b  = i >> 14;
  const short* src = qkv + ((size_t)(b * SEQ + tc * 8)) * QKVD + 1088 + d;
  short8 v;
#pragma unroll
  for (int e = 0; e < 8; ++e) v[e] = src[(size_t)e * QKVD];  // coalesced across lanes (d fast)
  *(short8*)(vt + ((size_t)(b * 64 + d)) * SEQ + tc * 8) = v;
}

// ---------------------------------------------------------------- MFMA flash MQA attention (swapped-QK^T)
// qkv bf16 [TOK][1152]; vtg bf16 [b][64][2048]; out bf16 [TOK][1024].
// Block 256 thr = 4 waves; block = (qt-slot, head, b); wave owns 16 q-rows.
// S^T = mfma(K,Q): lane (li,lg) holds q=li, t = n*16+lg*4+r  -> softmax needs only 2 shuffles.
// P repacked in-register (cvt_pk) and moved to PV A-frag via 16 ds_bpermute (no P LDS).
__global__ __launch_bounds__(256) void mqa_attn(
    const short* __restrict__ qkv, const short* __restrict__ vtg,
    short* __restrict__ out) {
  int head = blockIdx.y, b = blockIdx.z;
  // balanced qt mapping: pair (q, 31-q) on adjacent slots, rotate by head
  int s = (blockIdx.x + head * 8) & 31;
  int qt = (s & 1) ? (31 - (s >> 1)) : (s >> 1);
  int tid = threadIdx.x, wave = tid >> 6, lane = tid & 63;
  int li = lane & 15, lg = lane >> 4;

  __shared__ short Kc[64 * 72];   // [t][d], pad 8 -> conflict-free b128 r/w
  __shared__ short Vt[64 * 72];   // [d][t], staged from pre-transposed vtg

  const size_t qrow0 = (size_t)(b * SEQ + qt * 64);
  bf16x8 qf[2];   // B-frag: lane (li,lg) holds Q[q=li][kc*32+lg*8+e]
  {
    const short* qp = qkv + (qrow0 + wave * 16 + li) * QKVD + head * 64 + lg * 8;
    qf[0] = *(const bf16x8*)(qp);
    qf[1] = *(const bf16x8*)(qp + 32);
  }
  f32x4 oacc[4] = {};             // O: row q=lg*4+r, col d=dn*16+li
  float m_i = -1e30f, l_i = 0.f;  // per-lane softmax state for q = li (4x redundant over lg)

  int t_ = tid >> 3, c_ = tid & 7;
  const short* kg = qkv + (size_t)(b * SEQ) * QKVD + 1024;
  const short* vg = vtg + (size_t)(b * 64 + t_) * SEQ;

  for (int j = 0; j <= qt; ++j) {
    __syncthreads();              // LDS consumable again
    {
      const short* g0 = kg + (size_t)(j * 64 + t_) * QKVD + c_ * 8;
      short8 k0 = *(const short8*)(g0);
      short8 k1 = *(const short8*)(g0 + 32 * QKVD);
      short8 v0 = *(const short8*)(vg + j * 64 + c_ * 8);
      short8 v1 = *(const short8*)(vg + 32 * SEQ + j * 64 + c_ * 8);
      *(short8*)&Kc[t_ * 72 + c_ * 8] = k0;
      *(short8*)&Kc[(t_ + 32) * 72 + c_ * 8] = k1;
      *(short8*)&Vt[t_ * 72 + c_ * 8] = v0;
      *(short8*)&Vt[(t_ + 32) * 72 + c_ * 8] = v1;
    }
    __syncthreads();

    // S^T = K Q^T : 4 t-tiles x 2 k-chunks
    f32x4 s4[4];
#pragma unroll
    for (int n = 0; n < 4; ++n) {
      bf16x8 kf0 = *(const bf16x8*)&Kc[(n * 16 + li) * 72 + lg * 8];
      bf16x8 kf1 = *(const bf16x8*)&Kc[(n * 16 + li) * 72 + 32 + lg * 8];
      f32x4 a = {};
      a = MFMA16(kf0, qf[0], a);
      a = MFMA16(kf1, qf[1], a);
      s4[n] = a;
    }
    // scale + causal mask (lane's q = li, t = n*16+lg*4+r)
    bool diag = (j == qt);
    float p[4][4];
#pragma unroll
    for (int n = 0; n < 4; ++n)
#pragma unroll
      for (int r = 0; r < 4; ++r) {
        float v = s4[n][r] * 0.125f;
        if (diag && (n * 16 + lg * 4 + r) > (wave * 16 + li)) v = -1e30f;
        p[n][r] = v;
      }
    // online softmax: lane-local 16 values, then reduce across the 4 lg groups
    float mx = p[0][0];
#pragma unroll
    for (int n = 0; n < 4; ++n)
#pragma unroll
      for (int r = 0; r < 4; ++r) mx = fmaxf(mx, p[n][r]);
    mx = fmaxf(mx, __shfl_xor(mx, 16));
    mx = fmaxf(mx, __shfl_xor(mx, 32));
    float mn = fmaxf(m_i, mx);
    float alpha = __expf(m_i - mn);
    m_i = mn;
    float ps = 0.f;
#pragma unroll
    for (int n = 0; n < 4; ++n)
#pragma unroll
      for (int r = 0; r < 4; ++r) { float e = __expf(p[n][r] - mn); p[n][r] = e; ps += e; }
    ps += __shfl_xor(ps, 16);
    ps += __shfl_xor(ps, 32);
    l_i = l_i * alpha + ps;
    // O rescale: alpha lives at lanes with li == q; broadcast to O rows q = lg*4+r
    float arow[4];
#pragma unroll
    for (int r = 0; r < 4; ++r) arow[r] = __shfl(alpha, (lane >> 4) * 20 + r);
#pragma unroll
    for (int dn = 0; dn < 4; ++dn)
#pragma unroll
      for (int r = 0; r < 4; ++r) oacc[dn][r] *= arow[r];
    // pack P to bf16 dwords: pk[n][jj] = {p[n][2jj] lo, p[n][2jj+1] hi}
    unsigned pk[4][2];
#pragma unroll
    for (int n = 0; n < 4; ++n) {
      pk[n][0] = cvtpk_bf16(p[n][0], p[n][1]);
      pk[n][1] = cvtpk_bf16(p[n][2], p[n][3]);
    }
    // PV: A-frag lane (li,lg) needs P[q=li][t=ks*32+lg*8+e]
    //     <- src lane li+16*(2*(lg&1)+(d>>1)), src reg pk[2ks+(lg>>1)][d&1]
#pragma unroll
    for (int ks = 0; ks < 2; ++ks) {
      union { unsigned w[4]; bf16x8 v; } pu;
#pragma unroll
      for (int d = 0; d < 4; ++d) {
        int sl = (li + ((lg & 1) << 5) + ((d >> 1) << 4)) << 2;
        unsigned a0 = __builtin_amdgcn_ds_bpermute(sl, (int)pk[2 * ks][d & 1]);
        unsigned a1 = __builtin_amdgcn_ds_bpermute(sl, (int)pk[2 * ks + 1][d & 1]);
        pu.w[d] = (lg >> 1) ? a1 : a0;
      }
#pragma unroll
      for (int dn = 0; dn < 4; ++dn) {
        bf16x8 vf = *(const bf16x8*)&Vt[(dn * 16 + li) * 72 + ks * 32 + lg * 8];
        oacc[dn] = MFMA16(pu.v, vf, oacc[dn]);
      }
    }
  }
  // final: l lives at lanes with li == q; O rows are q = lg*4+r
  float lrow[4];
#pragma unroll
  for (int r = 0; r < 4; ++r) lrow[r] = __shfl(l_i, (lane >> 4) * 20 + r);
#pragma unroll
  for (int r = 0; r < 4; ++r) {
    float inv = 1.0f / lrow[r];
    size_t row = (qrow0 + wave * 16 + lg * 4 + r) * H + head * 64;
#pragma unroll
    for (int dn = 0; dn < 4; ++dn) out[row + dn * 16 + li] = f2bf(oacc[dn][r] * inv);
  }
}

// ---------------------------------------------------------------- launch
extern "C" void kernel_launch(void* const* d_in, const int* in_sizes, int n_in,
                              void* d_out, int out_size, void* d_ws, size_t ws_size,
                              hipStream_t stream) {
  const int*   input_ids    = (const int*)d_in[0];
  const int*   position_ids = (const int*)d_in[1];
  const float* wte     = (const float*)d_in[2];
  const float* wpe     = (const float*)d_in[3];
  const float* ln1_w   = (const float*)d_in[4];
  const float* ln1_b   = (const float*)d_in[5];
  const float* cattn_w = (const float*)d_in[6];
  const float* cattn_b = (const float*)d_in[7];
  const float* cproj_w = (const float*)d_in[8];
  const float* cproj_b = (const float*)d_in[9];
  const float* ln2_w   = (const float*)d_in[10];
  const float* ln2_b   = (const float*)d_in[11];
  const float* fc_w    = (const float*)d_in[12];
  const float* fc_b    = (const float*)d_in[13];
  const float* mproj_w = (const float*)d_in[14];
  const float* mproj_b = (const float*)d_in[15];
  const float* lnf_w   = (const float*)d_in[16];
  const float* lnf_b   = (const float*)d_in[17];

  float* h     = (float*)d_ws;                    // TOK*H f32
  short* xbf   = (short*)(h + (size_t)TOK * H);   // TOK*H bf16 (ln out / attn out)
  short* qkvbf = xbf + (size_t)TOK * H;           // TOK*QKVD bf16
  short* fcbf  = qkvbf + (size_t)TOK * QKVD;      // TOK*NI bf16
  short* wqkv  = fcbf + (size_t)TOK * NI;         // per-layer bf16 weights
  short* wcp   = wqkv + (size_t)QKVD * H;
  short* wfc   = wcp + (size_t)H * H;
  short* wmp   = wfc + (size_t)NI * H;
  short* vtg   = fcbf;   // V^T scratch [2][64][2048] bf16; fcbf unused until fc GEMM

  embed_kernel<<<TOK * H / 256, 256, 0, stream>>>(input_ids, position_ids, wte, wpe, h);

  for (int l = 0; l < LNUM; l++) {
    cast_kernel<<<QKVD * H / 1024, 256, 0, stream>>>(cattn_w + (size_t)l * QKVD * H, wqkv);
    cast_kernel<<<H * H / 1024, 256, 0, stream>>>(cproj_w + (size_t)l * H * H, wcp);
    cast_kernel<<<NI * H / 1024, 256, 0, stream>>>(fc_w + (size_t)l * NI * H, wfc);
    cast_kernel<<<H * NI / 1024, 256, 0, stream>>>(mproj_w + (size_t)l * H * NI, wmp);

    ln_kernel<true><<<TOK, 256, 0, stream>>>(h, ln1_w + l * H, ln1_b + l * H, xbf);
    gemm_mfma<0><<<dim3(QKVD / 128, TOK / 128), 256, 0, stream>>>(
        xbf, wqkv, cattn_b + (size_t)l * QKVD, qkvbf, TOK, QKVD, H);
    vtrans_kernel<<<(2 * 64 * SEQ / 8) / 256, 256, 0, stream>>>(qkvbf, vtg);
    mqa_attn<<<dim3(32, 16, BATCH), 256, 0, stream>>>(qkvbf, vtg, xbf);
    gemm_mfma<1><<<dim3(H / 128, TOK / 128), 256, 0, stream>>>(
        xbf, wcp, cproj_b + (size_t)l * H, h, TOK, H, H);
    ln_kernel<true><<<TOK, 256, 0, stream>>>(h, ln2_w + l * H, ln2_b + l * H, xbf);
    gemm_mfma<2><<<dim3(NI / 128, TOK / 128), 256, 0, stream>>>(
        xbf, wfc, fc_b + (size_t)l * NI, fcbf, TOK, NI, H);
    gemm_mfma<1><<<dim3(H / 128, TOK / 128), 256, 0, stream>>>(
        fcbf, wmp, mproj_b + (size_t)l * H, h, TOK, H, NI);
  }
  ln_kernel<false><<<TOK, 256, 0, stream>>>(h, lnf_w, lnf_b, d_out);
}

// Round 3
// 1675.003 us; speedup vs baseline: 1.1714x; 1.0950x over previous
//
#include <hip/hip_runtime.h>
#include <math.h>

typedef __attribute__((ext_vector_type(8))) short short8;
typedef __attribute__((ext_vector_type(8))) __bf16 bf16x8;
typedef __attribute__((ext_vector_type(4))) float f32x4;

static constexpr int H = 1024, LNUM = 4, SEQ = 2048, BATCH = 2;
static constexpr int TOK = BATCH * SEQ;       // 4096
static constexpr int NI = 4096, QKVD = H + 128; // 1152

__device__ __forceinline__ short f2bf(float f) {   // RNE fp32->bf16 bits
  union { float f; unsigned u; } c; c.f = f;
  return (short)((c.u + 0x7fffu + ((c.u >> 16) & 1u)) >> 16);
}

__device__ __forceinline__ void gl_lds16(const short* g, short* l) {
  __builtin_amdgcn_global_load_lds(
      (const __attribute__((address_space(1))) unsigned*)g,
      (__attribute__((address_space(3))) unsigned*)l, 16, 0, 0);
}

__device__ __forceinline__ unsigned cvtpk_bf16(float lo, float hi) {
  unsigned r;
  asm("v_cvt_pk_bf16_f32 %0, %1, %2" : "=v"(r) : "v"(lo), "v"(hi));
  return r;
}

#define MFMA16(a, b, c) __builtin_amdgcn_mfma_f32_16x16x32_bf16(a, b, c, 0, 0, 0)

// ---------------------------------------------------------------- embedding
__global__ __launch_bounds__(256) void embed_kernel(
    const int* __restrict__ ids, const int* __restrict__ pos,
    const float* __restrict__ wte, const float* __restrict__ wpe,
    float* __restrict__ h) {
  int i = blockIdx.x * 256 + threadIdx.x;
  int tok = i >> 10, d = i & 1023;
  h[i] = wte[(size_t)ids[tok] * H + d] + wpe[(size_t)pos[tok] * H + d];
}

// ---------------------------------------------------------------- fp32 -> bf16 cast (weights)
__global__ __launch_bounds__(256) void cast_kernel(
    const float* __restrict__ src, short* __restrict__ dst) {
  int i = blockIdx.x * 256 + threadIdx.x;
  float4 v = ((const float4*)src)[i];
  union { short s[4]; uint2 u; } p;
  p.s[0] = f2bf(v.x); p.s[1] = f2bf(v.y); p.s[2] = f2bf(v.z); p.s[3] = f2bf(v.w);
  ((uint2*)dst)[i] = p.u;
}

// ---------------------------------------------------------------- layernorm (fp32 in; bf16 or fp32 out)
template <bool BF16_OUT>
__global__ __launch_bounds__(256) void ln_kernel(
    const float* __restrict__ X, const float* __restrict__ w,
    const float* __restrict__ b, void* __restrict__ out) {
  int row = blockIdx.x;
  const float* x = X + (size_t)row * H;
  int tid = threadIdx.x, lane = tid & 63, wid = tid >> 6;
  float v[4];
#pragma unroll
  for (int i = 0; i < 4; i++) v[i] = x[tid + i * 256];
  float s = v[0] + v[1] + v[2] + v[3];
#pragma unroll
  for (int off = 32; off > 0; off >>= 1) s += __shfl_xor(s, off);
  __shared__ float red[8];
  if (lane == 0) red[wid] = s;
  __syncthreads();
  float mu = (red[0] + red[1] + red[2] + red[3]) * (1.0f / H);
  float q = 0.f;
#pragma unroll
  for (int i = 0; i < 4; i++) { float d = v[i] - mu; q += d * d; }
#pragma unroll
  for (int off = 32; off > 0; off >>= 1) q += __shfl_xor(q, off);
  if (lane == 0) red[4 + wid] = q;
  __syncthreads();
  float var = (red[4] + red[5] + red[6] + red[7]) * (1.0f / H);
  float inv = rsqrtf(var + 1e-5f);
#pragma unroll
  for (int i = 0; i < 4; i++) {
    int col = tid + i * 256;
    float r = (v[i] - mu) * inv * w[col] + b[col];
    if (BF16_OUT) ((short*)out)[(size_t)row * H + col] = f2bf(r);
    else          ((float*)out)[(size_t)row * H + col] = r;
  }
}

// ---------------------------------------------------------------- MFMA GEMM (legacy 128x128): C = A*W^T + bias
// MODE 0: C(bf16) = r   MODE 1: C(f32) += r   MODE 2: C(bf16) = gelu(r)
template <int MODE>
__global__ __launch_bounds__(256) void gemm_mfma(
    const short* __restrict__ A, const short* __restrict__ W,
    const float* __restrict__ bias, void* __restrict__ Cv,
    int M, int N, int K) {
  __shared__ short As[128 * 32];
  __shared__ short Bs[128 * 32];
  int tid = threadIdx.x, wave = tid >> 6, lane = tid & 63;
  int li = lane & 15, lg = lane >> 4;
  int row0 = blockIdx.y * 128, col0 = blockIdx.x * 128;
  int wm = (wave & 1) * 64, wn = (wave >> 1) * 64;
  f32x4 acc[4][4] = {};
  const short* Ab = A + (size_t)(row0 + (tid >> 2)) * K + (tid & 3) * 8;
  const short* Wb = W + (size_t)(col0 + (tid >> 2)) * K + (tid & 3) * 8;
  for (int k0 = 0; k0 < K; k0 += 32) {
    __syncthreads();
    gl_lds16(Ab + k0,            As + tid * 8);
    gl_lds16(Ab + k0 + 64 * K,   As + 2048 + tid * 8);
    gl_lds16(Wb + k0,            Bs + tid * 8);
    gl_lds16(Wb + k0 + 64 * K,   Bs + 2048 + tid * 8);
    __syncthreads();
    bf16x8 af[4], bfr[4];
#pragma unroll
    for (int i = 0; i < 4; ++i) {
      af[i]  = *(const bf16x8*)&As[(wm + i * 16 + li) * 32 + lg * 8];
      bfr[i] = *(const bf16x8*)&Bs[(wn + i * 16 + li) * 32 + lg * 8];
    }
#pragma unroll
    for (int i = 0; i < 4; ++i)
#pragma unroll
      for (int j = 0; j < 4; ++j) acc[i][j] = MFMA16(af[i], bfr[j], acc[i][j]);
  }
  float* Cf = (float*)Cv;
  short* Cs = (short*)Cv;
#pragma unroll
  for (int i = 0; i < 4; ++i) {
    int gr = row0 + wm + i * 16 + lg * 4;
#pragma unroll
    for (int j = 0; j < 4; ++j) {
      int gc = col0 + wn + j * 16 + li;
      float bv = bias[gc];
#pragma unroll
      for (int r = 0; r < 4; ++r) {
        float v = acc[i][j][r] + bv;
        size_t idx = (size_t)(gr + r) * N + gc;
        if (MODE == 1) {
          Cf[idx] += v;
        } else if (MODE == 2) {
          v = 0.5f * v * (1.0f + erff(v * 0.70710678118654752f));
          Cs[idx] = f2bf(v);
        } else {
          Cs[idx] = f2bf(v);
        }
      }
    }
  }
}

// ---------------------------------------------------------------- MFMA GEMM 256x256, BK=64, 8 waves, pipelined
// Counted-vmcnt double-buffer: prefetch 2 K-tiles deep; never drain vmcnt to 0 in steady state.
// LDS XOR-slot swizzle (involution, rule #21): physical slot p = logical ^ (row&7), applied on
// BOTH the global_load_lds source chunk and the ds_read address.
// MODE 1: atomicAdd into f32 C (split-K via blockIdx.z, K-chunk = 1024, bias only at z==0)
// MODE 2: C(bf16) = gelu(r)  (blockIdx.z == 0)
template <int MODE>
__global__ __launch_bounds__(512) void gemm256(
    const short* __restrict__ A, const short* __restrict__ W,
    const float* __restrict__ bias, void* __restrict__ Cv,
    int N, int K) {
  __shared__ short lds[2][2][256 * 64];   // [buf][A/B][row*64+col] 128 KiB
  int tid = threadIdx.x, wave = tid >> 6, lane = tid & 63;
  int li = lane & 15, lg = lane >> 4;
  // bijective XCD swizzle over (x,y); nwg is 256 (fc) or 64 (mproj per z) -> %8==0
  int gx = gridDim.x;
  int id = blockIdx.y * gx + blockIdx.x;
  int cpx = (gx * gridDim.y) >> 3;
  int swz = (id & 7) * cpx + (id >> 3);
  int bx = swz % gx, by = swz / gx;
  int row0 = by * 256, col0 = bx * 256;
  const short* Ab = A + (size_t)row0 * K + (blockIdx.z << 10);
  const short* Wb = W + (size_t)col0 * K + (blockIdx.z << 10);
  int wrow = (wave & 1) << 7, wcol = (wave >> 1) << 6;   // wave owns 128x64 of C
  f32x4 acc[8][4] = {};

  auto STAGE = [&](int t, int buf) {   // one K-tile: A 32KB + B 32KB, 8 loads/thread
#pragma unroll
    for (int i = 0; i < 4; ++i) {
      int c = i * 512 + tid, r = c >> 3, g = (c & 7) ^ (r & 7);
      gl_lds16(Ab + (size_t)r * K + t * 64 + g * 8, &lds[buf][0][c * 8]);
      gl_lds16(Wb + (size_t)r * K + t * 64 + g * 8, &lds[buf][1][c * 8]);
    }
  };
  STAGE(0, 0);
  STAGE(1, 1);
  for (int t = 0; t < 16; ++t) {       // K-chunk fixed at 16*64 = 1024
    int cur = t & 1;
    if (t < 15) { asm volatile("s_waitcnt vmcnt(8)" ::: "memory"); }  // tile t landed; t+1 in flight
    else        { asm volatile("s_waitcnt vmcnt(0)" ::: "memory"); }
    __builtin_amdgcn_s_barrier();      // collective: every wave's tile-t loads done
    asm volatile("" ::: "memory");
    const short* Al = lds[cur][0];
    const short* Bl = lds[cur][1];
    bf16x8 bfr[4][2];
#pragma unroll
    for (int j = 0; j < 4; ++j)
#pragma unroll
      for (int ks = 0; ks < 2; ++ks) {
        int rb = wcol + j * 16 + li;
        int sl = (ks * 4 + lg) ^ (rb & 7);
        bfr[j][ks] = *(const bf16x8*)&Bl[rb * 64 + sl * 8];
      }
#pragma unroll
    for (int q = 0; q < 4; ++q) {      // 4 phases x 16 MFMA
      bf16x8 afr[2][2];
#pragma unroll
      for (int m2 = 0; m2 < 2; ++m2)
#pragma unroll
        for (int ks = 0; ks < 2; ++ks) {
          int ra = wrow + (q * 2 + m2) * 16 + li;
          int sl = (ks * 4 + lg) ^ (ra & 7);
          afr[m2][ks] = *(const bf16x8*)&Al[ra * 64 + sl * 8];
        }
      __builtin_amdgcn_s_setprio(1);
#pragma unroll
      for (int m2 = 0; m2 < 2; ++m2)
#pragma unroll
        for (int j = 0; j < 4; ++j)
#pragma unroll
          for (int ks = 0; ks < 2; ++ks)
            acc[q * 2 + m2][j] = MFMA16(afr[m2][ks], bfr[j][ks], acc[q * 2 + m2][j]);
      __builtin_amdgcn_s_setprio(0);
    }
    asm volatile("" ::: "memory");
    __builtin_amdgcn_s_barrier();      // all waves done reading buf[cur]
    if (t + 2 < 16) STAGE(t + 2, cur); // overwrite now-free buffer; lands by t+2's vmcnt
  }
  // epilogue; C/D: col = li, row = lg*4 + reg
  float* Cf = (float*)Cv;
  short* Cs = (short*)Cv;
  bool addb = (blockIdx.z == 0);
#pragma unroll
  for (int i = 0; i < 8; ++i) {
    int gr = row0 + wrow + i * 16 + lg * 4;
#pragma unroll
    for (int j = 0; j < 4; ++j) {
      int gc = col0 + wcol + j * 16 + li;
      float bv = addb ? bias[gc] : 0.f;
#pragma unroll
      for (int r = 0; r < 4; ++r) {
        float v = acc[i][j][r] + bv;
        size_t idx = (size_t)(gr + r) * N + gc;
        if (MODE == 1) {
          atomicAdd(&Cf[idx], v);
        } else {
          v = 0.5f * v * (1.0f + erff(v * 0.70710678118654752f));
          Cs[idx] = f2bf(v);
        }
      }
    }
  }
}

// ---------------------------------------------------------------- V transpose: qkv V cols -> VT[b][d][t]
__global__ __launch_bounds__(256) void vtrans_kernel(
    const short* __restrict__ qkv, short* __restrict__ vt) {
  int i = blockIdx.x * 256 + threadIdx.x;   // 2*64*256 threads
  int d  = i & 63;
  int tc = (i >> 6) & 255;                  // t-chunk of 8
  int b  = i >> 14;
  const short* src = qkv + ((size_t)(b * SEQ + tc * 8)) * QKVD + 1088 + d;
  short8 v;
#pragma unroll
  for (int e = 0; e < 8; ++e) v[e] = src[(size_t)e * QKVD];  // coalesced across lanes (d fast)
  *(short8*)(vt + ((size_t)(b * 64 + d)) * SEQ + tc * 8) = v;
}

// ---------------------------------------------------------------- MFMA flash MQA attention (swapped-QK^T)
__global__ __launch_bounds__(256) void mqa_attn(
    const short* __restrict__ qkv, const short* __restrict__ vtg,
    short* __restrict__ out) {
  int head = blockIdx.y, b = blockIdx.z;
  int s = (blockIdx.x + head * 8) & 31;
  int qt = (s & 1) ? (31 - (s >> 1)) : (s >> 1);
  int tid = threadIdx.x, wave = tid >> 6, lane = tid & 63;
  int li = lane & 15, lg = lane >> 4;

  __shared__ short Kc[64 * 72];   // [t][d], pad 8 -> conflict-free b128 r/w
  __shared__ short Vt[64 * 72];   // [d][t], staged from pre-transposed vtg

  const size_t qrow0 = (size_t)(b * SEQ + qt * 64);
  bf16x8 qf[2];   // B-frag: lane (li,lg) holds Q[q=li][kc*32+lg*8+e]
  {
    const short* qp = qkv + (qrow0 + wave * 16 + li) * QKVD + head * 64 + lg * 8;
    qf[0] = *(const bf16x8*)(qp);
    qf[1] = *(const bf16x8*)(qp + 32);
  }
  f32x4 oacc[4] = {};             // O: row q=lg*4+r, col d=dn*16+li
  float m_i = -1e30f, l_i = 0.f;  // per-lane softmax state for q = li

  int t_ = tid >> 3, c_ = tid & 7;
  const short* kg = qkv + (size_t)(b * SEQ) * QKVD + 1024;
  const short* vg = vtg + (size_t)(b * 64 + t_) * SEQ;

  for (int j = 0; j <= qt; ++j) {
    __syncthreads();
    {
      const short* g0 = kg + (size_t)(j * 64 + t_) * QKVD + c_ * 8;
      short8 k0 = *(const short8*)(g0);
      short8 k1 = *(const short8*)(g0 + 32 * QKVD);
      short8 v0 = *(const short8*)(vg + j * 64 + c_ * 8);
      short8 v1 = *(const short8*)(vg + 32 * SEQ + j * 64 + c_ * 8);
      *(short8*)&Kc[t_ * 72 + c_ * 8] = k0;
      *(short8*)&Kc[(t_ + 32) * 72 + c_ * 8] = k1;
      *(short8*)&Vt[t_ * 72 + c_ * 8] = v0;
      *(short8*)&Vt[(t_ + 32) * 72 + c_ * 8] = v1;
    }
    __syncthreads();

    f32x4 s4[4];
#pragma unroll
    for (int n = 0; n < 4; ++n) {
      bf16x8 kf0 = *(const bf16x8*)&Kc[(n * 16 + li) * 72 + lg * 8];
      bf16x8 kf1 = *(const bf16x8*)&Kc[(n * 16 + li) * 72 + 32 + lg * 8];
      f32x4 a = {};
      a = MFMA16(kf0, qf[0], a);
      a = MFMA16(kf1, qf[1], a);
      s4[n] = a;
    }
    bool diag = (j == qt);
    float p[4][4];
#pragma unroll
    for (int n = 0; n < 4; ++n)
#pragma unroll
      for (int r = 0; r < 4; ++r) {
        float v = s4[n][r] * 0.125f;
        if (diag && (n * 16 + lg * 4 + r) > (wave * 16 + li)) v = -1e30f;
        p[n][r] = v;
      }
    float mx = p[0][0];
#pragma unroll
    for (int n = 0; n < 4; ++n)
#pragma unroll
      for (int r = 0; r < 4; ++r) mx = fmaxf(mx, p[n][r]);
    mx = fmaxf(mx, __shfl_xor(mx, 16));
    mx = fmaxf(mx, __shfl_xor(mx, 32));
    float mn = fmaxf(m_i, mx);
    float alpha = __expf(m_i - mn);
    m_i = mn;
    float ps = 0.f;
#pragma unroll
    for (int n = 0; n < 4; ++n)
#pragma unroll
      for (int r = 0; r < 4; ++r) { float e = __expf(p[n][r] - mn); p[n][r] = e; ps += e; }
    ps += __shfl_xor(ps, 16);
    ps += __shfl_xor(ps, 32);
    l_i = l_i * alpha + ps;
    float arow[4];
#pragma unroll
    for (int r = 0; r < 4; ++r) arow[r] = __shfl(alpha, (lane >> 4) * 20 + r);
#pragma unroll
    for (int dn = 0; dn < 4; ++dn)
#pragma unroll
      for (int r = 0; r < 4; ++r) oacc[dn][r] *= arow[r];
    unsigned pk[4][2];
#pragma unroll
    for (int n = 0; n < 4; ++n) {
      pk[n][0] = cvtpk_bf16(p[n][0], p[n][1]);
      pk[n][1] = cvtpk_bf16(p[n][2], p[n][3]);
    }
#pragma unroll
    for (int ks = 0; ks < 2; ++ks) {
      union { unsigned w[4]; bf16x8 v; } pu;
#pragma unroll
      for (int d = 0; d < 4; ++d) {
        int sl = (li + ((lg & 1) << 5) + ((d >> 1) << 4)) << 2;
        unsigned a0 = __builtin_amdgcn_ds_bpermute(sl, (int)pk[2 * ks][d & 1]);
        unsigned a1 = __builtin_amdgcn_ds_bpermute(sl, (int)pk[2 * ks + 1][d & 1]);
        pu.w[d] = (lg >> 1) ? a1 : a0;
      }
#pragma unroll
      for (int dn = 0; dn < 4; ++dn) {
        bf16x8 vf = *(const bf16x8*)&Vt[(dn * 16 + li) * 72 + ks * 32 + lg * 8];
        oacc[dn] = MFMA16(pu.v, vf, oacc[dn]);
      }
    }
  }
  float lrow[4];
#pragma unroll
  for (int r = 0; r < 4; ++r) lrow[r] = __shfl(l_i, (lane >> 4) * 20 + r);
#pragma unroll
  for (int r = 0; r < 4; ++r) {
    float inv = 1.0f / lrow[r];
    size_t row = (qrow0 + wave * 16 + lg * 4 + r) * H + head * 64;
#pragma unroll
    for (int dn = 0; dn < 4; ++dn) out[row + dn * 16 + li] = f2bf(oacc[dn][r] * inv);
  }
}

// ---------------------------------------------------------------- launch
extern "C" void kernel_launch(void* const* d_in, const int* in_sizes, int n_in,
                              void* d_out, int out_size, void* d_ws, size_t ws_size,
                              hipStream_t stream) {
  const int*   input_ids    = (const int*)d_in[0];
  const int*   position_ids = (const int*)d_in[1];
  const float* wte     = (const float*)d_in[2];
  const float* wpe     = (const float*)d_in[3];
  const float* ln1_w   = (const float*)d_in[4];
  const float* ln1_b   = (const float*)d_in[5];
  const float* cattn_w = (const float*)d_in[6];
  const float* cattn_b = (const float*)d_in[7];
  const float* cproj_w = (const float*)d_in[8];
  const float* cproj_b = (const float*)d_in[9];
  const float* ln2_w   = (const float*)d_in[10];
  const float* ln2_b   = (const float*)d_in[11];
  const float* fc_w    = (const float*)d_in[12];
  const float* fc_b    = (const float*)d_in[13];
  const float* mproj_w = (const float*)d_in[14];
  const float* mproj_b = (const float*)d_in[15];
  const float* lnf_w   = (const float*)d_in[16];
  const float* lnf_b   = (const float*)d_in[17];

  float* h     = (float*)d_ws;                    // TOK*H f32
  short* xbf   = (short*)(h + (size_t)TOK * H);   // TOK*H bf16 (ln out / attn out)
  short* qkvbf = xbf + (size_t)TOK * H;           // TOK*QKVD bf16
  short* fcbf  = qkvbf + (size_t)TOK * QKVD;      // TOK*NI bf16
  short* wqkv  = fcbf + (size_t)TOK * NI;         // per-layer bf16 weights
  short* wcp   = wqkv + (size_t)QKVD * H;
  short* wfc   = wcp + (size_t)H * H;
  short* wmp   = wfc + (size_t)NI * H;
  short* vtg   = fcbf;   // V^T scratch [2][64][2048] bf16; fcbf unused until fc GEMM

  embed_kernel<<<TOK * H / 256, 256, 0, stream>>>(input_ids, position_ids, wte, wpe, h);

  for (int l = 0; l < LNUM; l++) {
    cast_kernel<<<QKVD * H / 1024, 256, 0, stream>>>(cattn_w + (size_t)l * QKVD * H, wqkv);
    cast_kernel<<<H * H / 1024, 256, 0, stream>>>(cproj_w + (size_t)l * H * H, wcp);
    cast_kernel<<<NI * H / 1024, 256, 0, stream>>>(fc_w + (size_t)l * NI * H, wfc);
    cast_kernel<<<H * NI / 1024, 256, 0, stream>>>(mproj_w + (size_t)l * H * NI, wmp);

    ln_kernel<true><<<TOK, 256, 0, stream>>>(h, ln1_w + l * H, ln1_b + l * H, xbf);
    gemm_mfma<0><<<dim3(QKVD / 128, TOK / 128), 256, 0, stream>>>(
        xbf, wqkv, cattn_b + (size_t)l * QKVD, qkvbf, TOK, QKVD, H);
    vtrans_kernel<<<(2 * 64 * SEQ / 8) / 256, 256, 0, stream>>>(qkvbf, vtg);
    mqa_attn<<<dim3(32, 16, BATCH), 256, 0, stream>>>(qkvbf, vtg, xbf);
    gemm_mfma<1><<<dim3(H / 128, TOK / 128), 256, 0, stream>>>(
        xbf, wcp, cproj_b + (size_t)l * H, h, TOK, H, H);
    ln_kernel<true><<<TOK, 256, 0, stream>>>(h, ln2_w + l * H, ln2_b + l * H, xbf);
    // fc: M=4096, N=4096, K=1024 -> 16x16 blocks, gelu bf16 out
    gemm256<2><<<dim3(16, 16, 1), 512, 0, stream>>>(
        xbf, wfc, fc_b + (size_t)l * NI, fcbf, NI, H);
    // mproj: M=4096, N=1024, K=4096 -> split-K=4 (chunk 1024), atomic f32 += into h
    gemm256<1><<<dim3(4, 16, 4), 512, 0, stream>>>(
        fcbf, wmp, mproj_b + (size_t)l * H, h, H, NI);
  }
  ln_kernel<false><<<TOK, 256, 0, stream>>>(h, lnf_w, lnf_b, d_out);
}